// Round 1
// baseline (682.383 us; speedup 1.0000x reference)
//
#include <hip/hip_runtime.h>
#include <stdint.h>

#define NB 16      // NUM_BATCHES
#define K  32      // MAX_NUM_NEIGHBORS
#define R2 0.0625f // RADIUS^2 = 0.25^2, exact in f32

// Kernel 1: per-batch start offsets (batch is sorted) + squared norms.
// Writes ALL starts[0..NB] entries every call (ws is poisoned once by harness).
__global__ void radius_prep_kernel(const float* __restrict__ x,
                                   const int* __restrict__ batch,
                                   int n,
                                   int* __restrict__ starts,
                                   float* __restrict__ sq) {
#pragma clang fp contract(off)
    int i = blockIdx.x * blockDim.x + threadIdx.x;
    if (i >= n) return;
    float x0 = x[i * 3 + 0];
    float x1 = x[i * 3 + 1];
    float x2 = x[i * 3 + 2];
    // Match numpy: elementwise x*x then left-to-right sum — NO fma contraction.
    float p0 = x0 * x0;
    float p1 = x1 * x1;
    float p2 = x2 * x2;
    sq[i] = (p0 + p1) + p2;

    int b  = batch[i];
    int bp = (i == 0) ? -1 : batch[i - 1];
    for (int bb = bp + 1; bb <= b; ++bb) starts[bb] = i;
    if (i == n - 1) {
        for (int bb = b + 1; bb <= NB; ++bb) starts[bb] = n;
    }
}

// Kernel 2: one thread per target point. Scan the target's (contiguous) batch
// range, keep the 32 smallest (d2, j) keys in a per-thread sorted LDS list.
// Key packing: ordered-float bits of d2 in high 32, index j in low 32 ->
// uint64 min order == (d2 asc, j asc) == lax.top_k stable tie-break.
__global__ __launch_bounds__(256) void radius_knn_kernel(
    const float* __restrict__ x,
    const int* __restrict__ batch,
    const int* __restrict__ starts,
    const float* __restrict__ sq,
    int n,
    int* __restrict__ out,
    int row_stride /* = n*K */) {
#pragma clang fp contract(off)
    __shared__ uint64_t lds[K * 256];  // [slot][tid] column per thread, 64 KiB
    const int tid = threadIdx.x;
    const int i   = blockIdx.x * 256 + tid;
    if (i >= n) return;  // per-thread LDS columns only; no __syncthreads needed

    const int b = batch[i];
    const int s = starts[b];
    const int e = starts[b + 1];

    const float xi0 = x[i * 3 + 0];
    const float xi1 = x[i * 3 + 1];
    const float xi2 = x[i * 3 + 2];
    const float sqi = sq[i];

    uint64_t* L = lds + tid;  // element p at L[p*256]
    int c = 0;

    for (int j = s; j < e; ++j) {
        if (j == i) continue;
        float y0 = x[j * 3 + 0];
        float y1 = x[j * 3 + 1];
        float y2 = x[j * 3 + 2];
        // Match sgemm-style K=3 dot: fma chain accumulating from 0.
        float dot = xi0 * y0;
        dot = fmaf(xi1, y1, dot);
        dot = fmaf(xi2, y2, dot);
        float d2 = (sqi + sq[j]) - 2.0f * dot;
        if (!(d2 <= R2)) continue;
        d2 = d2 + 0.0f;  // normalize -0.0 -> +0.0 so tie-break matches float ==
        uint32_t u = __float_as_uint(d2);
        u = (u & 0x80000000u) ? ~u : (u | 0x80000000u);
        uint64_t key = ((uint64_t)u << 32) | (uint32_t)j;

        if (c == K) {
            if (key >= L[(K - 1) * 256]) continue;  // worse than current worst
            int p = K - 1;
            while (p > 0 && L[(p - 1) * 256] > key) {
                L[p * 256] = L[(p - 1) * 256];
                --p;
            }
            L[p * 256] = key;
        } else {
            int p = c;
            while (p > 0 && L[(p - 1) * 256] > key) {
                L[p * 256] = L[(p - 1) * 256];
                --p;
            }
            L[p * 256] = key;
            ++c;
        }
    }

    // Epilogue: row 0 = src (neighbor index), row 1 = tgt (= i), -1 padding.
    const long base = (long)i * K;
    for (int k = 0; k < K; ++k) {
        int srcv = -1;
        int tgtv = -1;
        if (k < c) {
            srcv = (int)(uint32_t)(L[k * 256] & 0xffffffffu);
            tgtv = i;
        }
        out[base + k]              = srcv;
        out[row_stride + base + k] = tgtv;
    }
}

extern "C" void kernel_launch(void* const* d_in, const int* in_sizes, int n_in,
                              void* d_out, int out_size, void* d_ws, size_t ws_size,
                              hipStream_t stream) {
    const float* x     = (const float*)d_in[0];
    const int*   batch = (const int*)d_in[1];
    const int    n     = in_sizes[1];          // 8192
    int*         out   = (int*)d_out;
    const int row_stride = out_size / 2;       // n*K

    // Workspace layout: starts[NB+1] at offset 0, sq[n] at offset 128.
    int*   starts = (int*)d_ws;
    float* sq     = (float*)((char*)d_ws + 128);

    const int threads = 256;
    const int blocks  = (n + threads - 1) / threads;

    radius_prep_kernel<<<blocks, threads, 0, stream>>>(x, batch, n, starts, sq);
    radius_knn_kernel<<<blocks, threads, 0, stream>>>(x, batch, starts, sq, n,
                                                      out, row_stride);
}

// Round 2
// 82.679 us; speedup vs baseline: 8.2534x; 8.2534x over previous
//
#include <hip/hip_runtime.h>
#include <stdint.h>

#define NB   16      // NUM_BATCHES
#define K    32      // MAX_NUM_NEIGHBORS
#define R2   0.0625f // RADIUS^2 = 0.25^2, exact in f32
#define MAXS 12      // per-lane candidate slots (covers batch range <= 64*12=768;
                     // batches are ~512 +/- 22, so this is >11 sigma of headroom)
#define WPB  4       // waves (targets) per block

// Kernel 1: per-batch start offsets (batch is sorted) + squared norms.
// Writes ALL starts[0..NB] entries every call (ws is poisoned once by harness).
__global__ void radius_prep_kernel(const float* __restrict__ x,
                                   const int* __restrict__ batch,
                                   int n,
                                   int* __restrict__ starts,
                                   float* __restrict__ sq) {
#pragma clang fp contract(off)
    int i = blockIdx.x * blockDim.x + threadIdx.x;
    if (i >= n) return;
    float x0 = x[i * 3 + 0];
    float x1 = x[i * 3 + 1];
    float x2 = x[i * 3 + 2];
    // Match numpy: elementwise x*x then left-to-right sum — NO fma contraction.
    float p0 = x0 * x0;
    float p1 = x1 * x1;
    float p2 = x2 * x2;
    sq[i] = (p0 + p1) + p2;

    int b  = batch[i];
    int bp = (i == 0) ? -1 : batch[i - 1];
    for (int bb = bp + 1; bb <= b; ++bb) starts[bb] = i;
    if (i == n - 1) {
        for (int bb = b + 1; bb <= NB; ++bb) starts[bb] = n;
    }
}

// Kernel 2: ONE WAVE (64 lanes) per target point.
//   scan : lane l takes candidates s+l, s+l+64, ... ; passing keys go into a
//          per-lane register slot array (compile-time indexed, no scratch).
//   merge: nsel = min(K, total) iterations of {per-lane slot-min, wave min-
//          reduce, winner removes slot}. Key = (ordered d2 bits << 32) | j,
//          so uint64 ascending == (d2 asc, j asc) == lax.top_k tie-break.
__global__ __launch_bounds__(256) void radius_knn_wave(
    const float* __restrict__ x,
    const int* __restrict__ batch,
    const int* __restrict__ starts,
    const float* __restrict__ sq,
    int n,
    int* __restrict__ out,
    int row_stride /* = n*K */) {
#pragma clang fp contract(off)
    const int tid  = threadIdx.x;
    const int lane = tid & 63;
    const int wid  = tid >> 6;
    const int i    = blockIdx.x * WPB + wid;
    if (i >= n) return;

    const int b = batch[i];
    const int s = starts[b];
    const int e = starts[b + 1];

    const float xi0 = x[i * 3 + 0];
    const float xi1 = x[i * 3 + 1];
    const float xi2 = x[i * 3 + 2];
    const float sqi = sq[i];

    uint64_t slot[MAXS];
#pragma unroll
    for (int p = 0; p < MAXS; ++p) slot[p] = UINT64_MAX;
    int c = 0;

    // ---- scan phase ----
    for (int j = s + lane; j < e; j += 64) {
        if (j == i) continue;
        float y0 = x[j * 3 + 0];
        float y1 = x[j * 3 + 1];
        float y2 = x[j * 3 + 2];
        // Match sgemm-style K=3 dot: fma chain accumulating from 0.
        float dot = xi0 * y0;
        dot = fmaf(xi1, y1, dot);
        dot = fmaf(xi2, y2, dot);
        float d2 = (sqi + sq[j]) - 2.0f * dot;
        if (!(d2 <= R2)) continue;
        d2 = d2 + 0.0f;  // normalize -0.0 -> +0.0
        uint32_t u = __float_as_uint(d2);
        u = (u & 0x80000000u) ? ~u : (u | 0x80000000u);
        uint64_t key = ((uint64_t)u << 32) | (uint32_t)j;

        if (c < MAXS) {
            // predicated write at compile-time index (keeps slots in VGPRs)
#pragma unroll
            for (int p = 0; p < MAXS; ++p)
                if (p == c) slot[p] = key;
            ++c;
        } else {
            // overflow safety net (unreachable for this input distribution):
            // replace the worst slot if the new key is better.
            int wp = 0;
            uint64_t wk = slot[0];
#pragma unroll
            for (int p = 1; p < MAXS; ++p)
                if (slot[p] > wk) { wk = slot[p]; wp = p; }
            if (key < wk) {
#pragma unroll
                for (int p = 0; p < MAXS; ++p)
                    if (p == wp) slot[p] = key;
            }
        }
    }

    // ---- total candidate count across the wave ----
    int cnt = c;
#pragma unroll
    for (int off = 1; off < 64; off <<= 1)
        cnt += __shfl_xor(cnt, off, 64);
    const int nsel = cnt < K ? cnt : K;

    // ---- merge phase: select nsel global minima, in order ----
    uint64_t sel = UINT64_MAX;
    for (int k = 0; k < nsel; ++k) {
        uint64_t m = slot[0];
#pragma unroll
        for (int p = 1; p < MAXS; ++p)
            m = slot[p] < m ? slot[p] : m;
        // wave-wide min reduce (64 lanes)
#pragma unroll
        for (int off = 1; off < 64; off <<= 1) {
            uint64_t o = (uint64_t)__shfl_xor((unsigned long long)m, off, 64);
            m = o < m ? o : m;
        }
        // winner lane removes its slot (keys are unique: j is unique)
#pragma unroll
        for (int p = 0; p < MAXS; ++p)
            if (slot[p] == m) slot[p] = UINT64_MAX;
        if (lane == k) sel = m;
    }

    // ---- epilogue: row 0 = src (lanes 0..31), row 1 = tgt (lanes 32..63) ----
    const long base = (long)i * K;
    if (lane < K) {
        int srcv = (sel == UINT64_MAX) ? -1 : (int)(uint32_t)(sel & 0xffffffffu);
        out[base + lane] = srcv;
    } else {
        int l2 = lane - K;
        out[row_stride + base + l2] = (l2 < nsel) ? i : -1;
    }
}

extern "C" void kernel_launch(void* const* d_in, const int* in_sizes, int n_in,
                              void* d_out, int out_size, void* d_ws, size_t ws_size,
                              hipStream_t stream) {
    const float* x     = (const float*)d_in[0];
    const int*   batch = (const int*)d_in[1];
    const int    n     = in_sizes[1];          // 8192
    int*         out   = (int*)d_out;
    const int row_stride = out_size / 2;       // n*K

    // Workspace layout: starts[NB+1] at offset 0, sq[n] at offset 128.
    int*   starts = (int*)d_ws;
    float* sq     = (float*)((char*)d_ws + 128);

    radius_prep_kernel<<<(n + 255) / 256, 256, 0, stream>>>(x, batch, n, starts, sq);

    const int blocks = (n + WPB - 1) / WPB;    // one wave per target
    radius_knn_wave<<<blocks, 256, 0, stream>>>(x, batch, starts, sq, n,
                                                out, row_stride);
}

// Round 3
// 17.664 us; speedup vs baseline: 38.6315x; 4.6807x over previous
//
#include <hip/hip_runtime.h>
#include <stdint.h>

#define NB   16      // NUM_BATCHES
#define K    32      // MAX_NUM_NEIGHBORS
#define R2   0.0625f // RADIUS^2 = 0.25^2, exact in f32
#define WPB  4       // waves (targets) per block
#define MAXC 256     // per-wave candidate buffer (observed max ~60; >=6 sigma)

// Kernel 1: per-batch start offsets (batch is sorted) + squared norms.
// Writes ALL starts[0..NB] entries every call (ws is poisoned once by harness).
__global__ void radius_prep_kernel(const float* __restrict__ x,
                                   const int* __restrict__ batch,
                                   int n,
                                   int* __restrict__ starts,
                                   float* __restrict__ sq) {
#pragma clang fp contract(off)
    int i = blockIdx.x * blockDim.x + threadIdx.x;
    if (i >= n) return;
    float x0 = x[i * 3 + 0];
    float x1 = x[i * 3 + 1];
    float x2 = x[i * 3 + 2];
    // Match numpy: elementwise x*x then left-to-right sum — NO fma contraction.
    float p0 = x0 * x0;
    float p1 = x1 * x1;
    float p2 = x2 * x2;
    sq[i] = (p0 + p1) + p2;

    int b  = batch[i];
    int bp = (i == 0) ? -1 : batch[i - 1];
    for (int bb = bp + 1; bb <= b; ++bb) starts[bb] = i;
    if (i == n - 1) {
        for (int bb = b + 1; bb <= NB; ++bb) starts[bb] = n;
    }
}

// Kernel 2: ONE WAVE per target.
//   scan : wave-uniform trip count; passing keys compacted into per-wave LDS
//          buffer via ballot + prefix popcount (no atomics).
//   rank : lane p computes rank of key p by comparing against all cnt keys
//          (broadcast LDS reads). rank < K -> scatter src index into res[rank].
//   Key = (ordered d2 bits << 32) | j  ->  uint64 ascending == (d2 asc, j asc)
//   == lax.top_k stable tie-break. Identical FP path to the passing kernel.
__global__ __launch_bounds__(256) void radius_knn_wave(
    const float* __restrict__ x,
    const int* __restrict__ batch,
    const int* __restrict__ starts,
    const float* __restrict__ sq,
    int n,
    int* __restrict__ out,
    int row_stride /* = n*K */) {
#pragma clang fp contract(off)
    __shared__ uint64_t buf[WPB][MAXC];
    __shared__ int      res[WPB][K];

    const int tid  = threadIdx.x;
    const int lane = tid & 63;
    const int wid  = tid >> 6;
    const int i    = blockIdx.x * WPB + wid;   // n % WPB == 0: no early return

    const int b = batch[i];
    const int s = starts[b];
    const int e = starts[b + 1];

    const float xi0 = x[i * 3 + 0];
    const float xi1 = x[i * 3 + 1];
    const float xi2 = x[i * 3 + 2];
    const float sqi = sq[i];

    // ---- scan + ballot-compaction (wave-uniform trip count) ----
    const int range = e - s;
    const int iters = (range + 63) >> 6;
    int cbase = 0;
    for (int it = 0; it < iters; ++it) {
        const int j  = s + it * 64 + lane;
        const int jc = (j < e) ? j : s;        // clamp for safe loads
        float y0 = x[jc * 3 + 0];
        float y1 = x[jc * 3 + 1];
        float y2 = x[jc * 3 + 2];
        float dot = xi0 * y0;                  // sgemm-style K=3 fma chain
        dot = fmaf(xi1, y1, dot);
        dot = fmaf(xi2, y2, dot);
        float d2 = (sqi + sq[jc]) - 2.0f * dot;
        bool pass = (j < e) && (j != i) && (d2 <= R2);

        d2 = d2 + 0.0f;                        // normalize -0.0 -> +0.0
        uint32_t u = __float_as_uint(d2);
        u = (u & 0x80000000u) ? ~u : (u | 0x80000000u);
        uint64_t key = ((uint64_t)u << 32) | (uint32_t)jc;

        uint64_t mask = __ballot(pass);
        if (pass) {
            int off = cbase + __popcll(mask & ((1ull << lane) - 1ull));
            if (off < MAXC) buf[wid][off] = key;
        }
        cbase += (int)__popcll(mask);
    }
    int cnt = cbase < MAXC ? cbase : MAXC;
    const int nsel = cnt < K ? cnt : K;

    __syncthreads();   // buf visible to all lanes (uniform: every thread reaches)

    // ---- rank + scatter: lane p ranks key p against all cnt keys ----
    for (int p = lane; p < cnt; p += 64) {
        uint64_t kp = buf[wid][p];
        int r = 0;
        for (int q = 0; q < cnt; ++q)
            r += (buf[wid][q] < kp) ? 1 : 0;
        if (r < K) res[wid][r] = (int)(uint32_t)(kp & 0xffffffffu);
    }

    __syncthreads();   // res visible (uniform)

    // ---- epilogue: row 0 = src (lanes 0..31), row 1 = tgt (lanes 32..63) ----
    const long base = (long)i * K;
    if (lane < K) {
        out[base + lane] = (lane < nsel) ? res[wid][lane] : -1;
    } else {
        const int l2 = lane - K;
        out[row_stride + base + l2] = (l2 < nsel) ? i : -1;
    }
}

extern "C" void kernel_launch(void* const* d_in, const int* in_sizes, int n_in,
                              void* d_out, int out_size, void* d_ws, size_t ws_size,
                              hipStream_t stream) {
    const float* x     = (const float*)d_in[0];
    const int*   batch = (const int*)d_in[1];
    const int    n     = in_sizes[1];          // 8192
    int*         out   = (int*)d_out;
    const int row_stride = out_size / 2;       // n*K

    // Workspace layout: starts[NB+1] at offset 0, sq[n] at offset 128.
    int*   starts = (int*)d_ws;
    float* sq     = (float*)((char*)d_ws + 128);

    radius_prep_kernel<<<(n + 255) / 256, 256, 0, stream>>>(x, batch, n, starts, sq);

    const int blocks = n / WPB;                // one wave per target
    radius_knn_wave<<<blocks, 256, 0, stream>>>(x, batch, starts, sq, n,
                                                out, row_stride);
}

// Round 4
// 15.391 us; speedup vs baseline: 44.3372x; 1.1477x over previous
//
#include <hip/hip_runtime.h>
#include <stdint.h>

#define NB   16      // NUM_BATCHES
#define K    32      // MAX_NUM_NEIGHBORS
#define R2   0.0625f // RADIUS^2 = 0.25^2, exact in f32
#define WPB  4       // waves (targets) per block
#define MAXC 256     // per-wave candidate buffer (observed max ~60; >=6 sigma)

// Single fused kernel: ONE WAVE per target.
//   bounds: per-wave binary search on the sorted batch array (13 uniform
//           iterations each for lower_bound(b) / lower_bound(b+1)).
//   scan  : wave-uniform trip count; sq[j] recomputed inline from x[j] with
//           the exact numpy expression (contract off) -> bit-identical.
//           Passing keys compacted into per-wave LDS via ballot + popcount.
//   rank  : lane p ranks key p against all cnt keys (broadcast LDS reads);
//           rank < K -> scatter src index into res[rank].
//   Key = (ordered d2 bits << 32) | j  ->  uint64 ascending == (d2 asc, j asc)
//   == lax.top_k stable tie-break. FP path identical to the passing kernel.
__global__ __launch_bounds__(256) void radius_knn_fused(
    const float* __restrict__ x,
    const int* __restrict__ batch,
    int n,
    int* __restrict__ out,
    int row_stride /* = n*K */) {
#pragma clang fp contract(off)
    __shared__ uint64_t buf[WPB][MAXC];
    __shared__ int      res[WPB][K];

    const int tid  = threadIdx.x;
    const int lane = tid & 63;
    const int wid  = tid >> 6;
    const int i    = blockIdx.x * WPB + wid;   // n % WPB == 0: no early return

    const int b = batch[i];

    // ---- batch range via binary search (wave-uniform, 13 iters each) ----
    int lo = 0, hi = n;
    while (lo < hi) {
        int mid = (lo + hi) >> 1;
        if (batch[mid] < b) lo = mid + 1; else hi = mid;
    }
    const int s = lo;
    int lo2 = s, hi2 = n;
    while (lo2 < hi2) {
        int mid = (lo2 + hi2) >> 1;
        if (batch[mid] <= b) lo2 = mid + 1; else hi2 = mid;
    }
    const int e = lo2;

    // ---- target point + its squared norm (numpy-exact: no contraction) ----
    const float xi0 = x[i * 3 + 0];
    const float xi1 = x[i * 3 + 1];
    const float xi2 = x[i * 3 + 2];
    const float q0 = xi0 * xi0, q1 = xi1 * xi1, q2 = xi2 * xi2;
    const float sqi = (q0 + q1) + q2;

    // ---- scan + ballot-compaction (wave-uniform trip count) ----
    const int range = e - s;
    const int iters = (range + 63) >> 6;
    int cbase = 0;
    for (int it = 0; it < iters; ++it) {
        const int j  = s + it * 64 + lane;
        const int jc = (j < e) ? j : s;        // clamp for safe loads
        float y0 = x[jc * 3 + 0];
        float y1 = x[jc * 3 + 1];
        float y2 = x[jc * 3 + 2];
        // sq[j] inline, identical expression to numpy's elementwise square+sum
        float p0 = y0 * y0, p1 = y1 * y1, p2 = y2 * y2;
        float sqj = (p0 + p1) + p2;
        // sgemm-style K=3 dot: fma chain accumulating from 0.
        float dot = xi0 * y0;
        dot = fmaf(xi1, y1, dot);
        dot = fmaf(xi2, y2, dot);
        float d2 = (sqi + sqj) - 2.0f * dot;
        bool pass = (j < e) && (j != i) && (d2 <= R2);

        d2 = d2 + 0.0f;                        // normalize -0.0 -> +0.0
        uint32_t u = __float_as_uint(d2);
        u = (u & 0x80000000u) ? ~u : (u | 0x80000000u);
        uint64_t key = ((uint64_t)u << 32) | (uint32_t)jc;

        uint64_t mask = __ballot(pass);
        if (pass) {
            int off = cbase + __popcll(mask & ((1ull << lane) - 1ull));
            if (off < MAXC) buf[wid][off] = key;
        }
        cbase += (int)__popcll(mask);
    }
    int cnt = cbase < MAXC ? cbase : MAXC;
    const int nsel = cnt < K ? cnt : K;

    __syncthreads();   // buf visible (uniform: every thread reaches)

    // ---- rank + scatter: lane p ranks key p against all cnt keys ----
    for (int p = lane; p < cnt; p += 64) {
        uint64_t kp = buf[wid][p];
        int r = 0;
        for (int q = 0; q < cnt; ++q)
            r += (buf[wid][q] < kp) ? 1 : 0;
        if (r < K) res[wid][r] = (int)(uint32_t)(kp & 0xffffffffu);
    }

    __syncthreads();   // res visible (uniform)

    // ---- epilogue: row 0 = src (lanes 0..31), row 1 = tgt (lanes 32..63) ----
    const long base = (long)i * K;
    if (lane < K) {
        out[base + lane] = (lane < nsel) ? res[wid][lane] : -1;
    } else {
        const int l2 = lane - K;
        out[row_stride + base + l2] = (l2 < nsel) ? i : -1;
    }
}

extern "C" void kernel_launch(void* const* d_in, const int* in_sizes, int n_in,
                              void* d_out, int out_size, void* d_ws, size_t ws_size,
                              hipStream_t stream) {
    const float* x     = (const float*)d_in[0];
    const int*   batch = (const int*)d_in[1];
    const int    n     = in_sizes[1];          // 8192
    int*         out   = (int*)d_out;
    const int row_stride = out_size / 2;       // n*K

    const int blocks = n / WPB;                // one wave per target
    radius_knn_fused<<<blocks, 256, 0, stream>>>(x, batch, n, out, row_stride);
}

// Round 5
// 14.282 us; speedup vs baseline: 47.7791x; 1.0776x over previous
//
#include <hip/hip_runtime.h>
#include <stdint.h>

#define NB   16      // NUM_BATCHES
#define K    32      // MAX_NUM_NEIGHBORS
#define R2   0.0625f // RADIUS^2 = 0.25^2, exact in f32
#define WPB  4       // waves (targets) per block
#define MAXC 256     // per-wave candidate buffer (observed max ~60; >=6 sigma)

// Single fused kernel: ONE WAVE per target.
//   bounds: threads 0..NB of each block binary-search lower_bound(batch, tid)
//           in PARALLEL -> sstart[NB+1] in LDS (one 13-load latency chain per
//           block instead of two per wave).
//   scan  : wave-uniform trip count, software-pipelined (prefetch next point
//           while compacting current). sq[j] recomputed inline from x[j] with
//           the exact numpy expression (contract off) -> bit-identical.
//           Passing keys compacted into per-wave LDS via ballot + popcount.
//   rank  : lane p ranks key p against all cnt keys (broadcast LDS reads);
//           rank < K -> scatter src index into res[rank].
//   Key = (ordered d2 bits << 32) | j  ->  uint64 ascending == (d2 asc, j asc)
//   == lax.top_k stable tie-break. FP path identical to the passing kernel.
__global__ __launch_bounds__(256) void radius_knn_fused(
    const float* __restrict__ x,
    const int* __restrict__ batch,
    int n,
    int* __restrict__ out,
    int row_stride /* = n*K */) {
#pragma clang fp contract(off)
    __shared__ uint64_t buf[WPB][MAXC];
    __shared__ int      res[WPB][K];
    __shared__ int      sstart[NB + 1];

    const int tid  = threadIdx.x;
    const int lane = tid & 63;
    const int wid  = tid >> 6;
    const int i    = blockIdx.x * WPB + wid;   // n % WPB == 0: no early return

    // ---- cooperative batch bounds: 17 parallel binary searches ----
    if (tid <= NB) {
        const int target = tid;                // lower_bound(batch, target)
        int lo = 0, hi = n;
        while (lo < hi) {
            int mid = (lo + hi) >> 1;
            if (batch[mid] < target) lo = mid + 1; else hi = mid;
        }
        sstart[tid] = lo;
    }
    __syncthreads();

    const int b = batch[i];
    const int s = sstart[b];
    const int e = sstart[b + 1];

    // ---- target point + its squared norm (numpy-exact: no contraction) ----
    const float xi0 = x[i * 3 + 0];
    const float xi1 = x[i * 3 + 1];
    const float xi2 = x[i * 3 + 2];
    const float q0 = xi0 * xi0, q1 = xi1 * xi1, q2 = xi2 * xi2;
    const float sqi = (q0 + q1) + q2;

    // ---- scan + ballot-compaction, software-pipelined ----
    const int range = e - s;
    const int iters = (range + 63) >> 6;
    int cbase = 0;

    int j  = s + lane;
    int jc = (j < e) ? j : s;                  // clamp for safe loads
    float y0 = x[jc * 3 + 0];
    float y1 = x[jc * 3 + 1];
    float y2 = x[jc * 3 + 2];

    for (int it = 0; it < iters; ++it) {
        // prefetch next iteration's point (clamped address is always valid)
        const int jn  = j + 64;
        const int jnc = (jn < e) ? jn : s;
        const float z0 = x[jnc * 3 + 0];
        const float z1 = x[jnc * 3 + 1];
        const float z2 = x[jnc * 3 + 2];

        // sq[j] inline, identical expression to numpy's elementwise square+sum
        float p0 = y0 * y0, p1 = y1 * y1, p2 = y2 * y2;
        float sqj = (p0 + p1) + p2;
        // sgemm-style K=3 dot: fma chain accumulating from 0.
        float dot = xi0 * y0;
        dot = fmaf(xi1, y1, dot);
        dot = fmaf(xi2, y2, dot);
        float d2 = (sqi + sqj) - 2.0f * dot;
        bool pass = (j < e) && (j != i) && (d2 <= R2);

        d2 = d2 + 0.0f;                        // normalize -0.0 -> +0.0
        uint32_t u = __float_as_uint(d2);
        u = (u & 0x80000000u) ? ~u : (u | 0x80000000u);
        uint64_t key = ((uint64_t)u << 32) | (uint32_t)jc;

        uint64_t mask = __ballot(pass);
        if (pass) {
            int off = cbase + __popcll(mask & ((1ull << lane) - 1ull));
            if (off < MAXC) buf[wid][off] = key;
        }
        cbase += (int)__popcll(mask);

        j = jn; jc = jnc; y0 = z0; y1 = z1; y2 = z2;
    }
    int cnt = cbase < MAXC ? cbase : MAXC;
    const int nsel = cnt < K ? cnt : K;

    __syncthreads();   // buf visible (uniform: every thread reaches)

    // ---- rank + scatter: lane p ranks key p against all cnt keys ----
    for (int p = lane; p < cnt; p += 64) {
        uint64_t kp = buf[wid][p];
        int r = 0;
        for (int q = 0; q < cnt; ++q)
            r += (buf[wid][q] < kp) ? 1 : 0;
        if (r < K) res[wid][r] = (int)(uint32_t)(kp & 0xffffffffu);
    }

    __syncthreads();   // res visible (uniform)

    // ---- epilogue: row 0 = src (lanes 0..31), row 1 = tgt (lanes 32..63) ----
    const long base = (long)i * K;
    if (lane < K) {
        out[base + lane] = (lane < nsel) ? res[wid][lane] : -1;
    } else {
        const int l2 = lane - K;
        out[row_stride + base + l2] = (l2 < nsel) ? i : -1;
    }
}

extern "C" void kernel_launch(void* const* d_in, const int* in_sizes, int n_in,
                              void* d_out, int out_size, void* d_ws, size_t ws_size,
                              hipStream_t stream) {
    const float* x     = (const float*)d_in[0];
    const int*   batch = (const int*)d_in[1];
    const int    n     = in_sizes[1];          // 8192
    int*         out   = (int*)d_out;
    const int row_stride = out_size / 2;       // n*K

    const int blocks = n / WPB;                // one wave per target
    radius_knn_fused<<<blocks, 256, 0, stream>>>(x, batch, n, out, row_stride);
}